// Round 9
// baseline (387.144 us; speedup 1.0000x reference)
//
#include <hip/hip_runtime.h>

// ---------------- problem constants ----------------
constexpr int cN     = 20000;
constexpr int cT     = 8;
constexpr int cFIN   = 64;
constexpr int cHEADS = 4;
constexpr int cF     = 32;
constexpr int cHID   = 128;        // cHEADS * cF
constexpr int cE     = 320000;
constexpr int cET    = cE + cN;    // edges + self loops
constexpr int cR     = cN * cT;    // 160000 batched rows, rho = t*N + n (t-major)
constexpr int cSCAT  = (cET + 255) / 256;   // scatter blocks in the fused dispatch
constexpr int cWIN   = 800;        // degree-sort window (25 windows, 50 blocks each)
constexpr int cNW    = cN / cWIN;  // 25
constexpr float cLEAKY = 0.2f;
constexpr float cL2E = 1.44269504088896340736f;   // log2(e)

// pi-storage v2 (HEAD-LOCAL): storage dword d = h*16 + mi holds the bf16 pair
// (feature 32h+mi, feature 32h+16+mi). feat(p) = 32*(p>>5) + ((p>>1)&15) + 16*(p&1).
// Head h occupies contiguous bytes [64h, 64h+64) of each 256B row, so an agg
// lane's 16B slice (dwords 4j..4j+3) is entirely within head j>>2.
// MFMA K-permutation is free as long as A and B agree: W2bP/lw1bP/b1P/b2P are
// permuted once at cvt time; h tiles are written directly from accumulators.
//
// Windowed degree-sort perm (r3's gather win, parallelized): nodes sorted by
// degree WITHIN 800-node windows -> the 16 rows of an agg block have ~equal
// degree (no max-degree slack in the wave loop) while all metadata/output
// accesses stay in an 800-node range (L2 locality preserved; global sort
// destroyed it, r2 FETCH 137->175 MB).

typedef __attribute__((ext_vector_type(8))) short bf16x8;   // MFMA A/B frag
typedef __attribute__((ext_vector_type(4))) float f32x4;    // MFMA C/D frag
typedef __attribute__((ext_vector_type(2))) float f32x2;    // packed fp32 (v_pk_fma_f32)

static __device__ __forceinline__ unsigned short f2bfu(float f) {
    unsigned int u;
    __builtin_memcpy(&u, &f, 4);
    u += 0x7FFFu + ((u >> 16) & 1u);
    return (unsigned short)(u >> 16);
}
static __device__ __forceinline__ f32x2 bfp2(unsigned int v) {
    unsigned int ul = v << 16, uh = v & 0xFFFF0000u;
    float lo, hi;
    __builtin_memcpy(&lo, &ul, 4);
    __builtin_memcpy(&hi, &uh, 4);
    return (f32x2){lo, hi};
}
static __device__ __forceinline__ unsigned int pack2(float lo, float hi) {
    unsigned int ul, uh;
    __builtin_memcpy(&ul, &lo, 4);
    __builtin_memcpy(&uh, &hi, 4);
    ul += 0x7FFFu + ((ul >> 16) & 1u);
    uh += 0x7FFFu + ((uh >> 16) & 1u);
    return (ul >> 16) | (uh & 0xFFFF0000u);
}
static __device__ __forceinline__ int featOf(int p) {   // pi-v2 storage -> semantic feature
    return ((p >> 5) << 5) + ((p >> 1) & 15) + ((p & 1) << 4);
}

// ---------------- fused weight conversion (pi-v2 permute) + degree count ----------------
__global__ void cvt_deg_kernel(const float* W1, const float* W2, const float* lw1,
                               const float* b1, const float* b2, const int* ei,
                               unsigned short* W1b, unsigned short* W2bP,
                               unsigned short* lw1bP, float* b1P, float* b2P, int* deg) {
    int i = blockIdx.x * 256 + threadIdx.x;
    if (i < 8192) {                                   // W1b plain (K = x-features, linear)
        W1b[i] = f2bfu(W1[i]);
    } else if (i < 8192 + 16384) {                    // W2bP: K permuted to pi-v2 storage
        int jj = i - 8192;
        int c = jj >> 7, p = jj & 127;
        W2bP[jj] = f2bfu(W2[c * cHID + featOf(p)]);
    } else if (i < 8192 + 16384 + 4096) {             // lw1bP: K permuted
        int jj = i - 8192 - 16384;
        int c = jj >> 7, p = jj & 127;
        lw1bP[jj] = f2bfu(lw1[c * cHID + featOf(p)]);
    } else if (i < 8192 + 16384 + 4096 + 128) {       // b1P
        int p = i - 8192 - 16384 - 4096;
        b1P[p] = b1[featOf(p)];
    } else if (i < 8192 + 16384 + 4096 + 256) {       // b2P
        int p = i - 8192 - 16384 - 4096 - 128;
        b2P[p] = b2[featOf(p)];
    }
    if (i < cE) atomicAdd(&deg[ei[cE + i]], 1);
}

// LDS-staged scan (self-loop +1 folded) + PARALLEL windowed counting sort.
// All 25 windows histogrammed/scanned/scattered concurrently (r3's serial
// per-window version cost ~15-20us on one block; this is ~2-3us).
__global__ void scan_kernel(const int* deg, int* offs, int* cur, int* perm) {
    __shared__ int sdeg[79 * 256];     // 20224 >= cN (80.9 KB)
    __shared__ int lds[256];
    __shared__ int hbin[cNW * 64];     // 25 windows x 64 bins (6.4 KB)
    int tid = threadIdx.x;
    #pragma unroll 4
    for (int k = 0; k < 79; k++) {
        int idx = k * 256 + tid;
        sdeg[idx] = (idx < cN) ? deg[idx] + 1 : 0;
    }
    for (int k = tid; k < cNW * 64; k += 256) hbin[k] = 0;
    __syncthreads();
    const int CH = 79;
    int base = tid * CH;
    int tot = 0;
    #pragma unroll 8
    for (int j = 0; j < CH; j++) tot += sdeg[base + j];
    lds[tid] = tot;
    __syncthreads();
    for (int off = 1; off < 256; off <<= 1) {
        int v = (tid >= off) ? lds[tid - off] : 0;
        __syncthreads();
        lds[tid] += v;
        __syncthreads();
    }
    int run = lds[tid] - tot;
    for (int j = 0; j < CH; j++) {
        int idx = base + j;
        if (idx < cN) { offs[idx] = run; cur[idx] = run; run += sdeg[idx]; }
    }
    if (tid == 255) offs[cN] = lds[255];

    // ---- windowed counting sort -> perm (all windows in parallel) ----
    for (int k = tid; k < cN; k += 256)
        atomicAdd(&hbin[(k / cWIN) * 64 + min(sdeg[k], 63)], 1);
    __syncthreads();
    if (tid < cNW) {                   // thread w: exclusive scan of window w's 64 bins
        int r2 = tid * cWIN;
        #pragma unroll 8
        for (int bb = 0; bb < 64; bb++) {
            int c = hbin[tid * 64 + bb];
            hbin[tid * 64 + bb] = r2;
            r2 += c;
        }
    }
    __syncthreads();
    for (int k = tid; k < cN; k += 256) {
        int pos = atomicAdd(&hbin[(k / cWIN) * 64 + min(sdeg[k], 63)], 1);
        perm[pos] = k;
    }
}

// ---------------- fused CSR-scatter + GEMM1 (independent work, one dispatch) ----------------
// blocks [0,cSCAT): scatter edges into csr. blocks [cSCAT, cSCAT+cR/64): gemm1.
// gemm1: zero-LDS, direct pi-v2 write, register-shuffle scores.
__global__ __launch_bounds__(256) void scatter_gemm1_kernel(
        const int* __restrict__ ei, int* __restrict__ cur, int* __restrict__ csr,
        const float* __restrict__ x, const unsigned short* __restrict__ W,
        const float* __restrict__ a_src, const float* __restrict__ a_dst,
        unsigned short* __restrict__ hb, float* __restrict__ es, float* __restrict__ ed) {
    int b = blockIdx.x;
    if (b < cSCAT) {
        int e = b * 256 + threadIdx.x;
        if (e >= cET) return;
        int s, d;
        if (e < cE) { s = ei[e]; d = ei[cE + e]; }
        else        { s = e - cE; d = s; }
        int pos = atomicAdd(&cur[d], 1);
        csr[pos] = s;
        return;
    }
    int gb   = b - cSCAT;
    int tid  = threadIdx.x;
    int wave = tid >> 6;
    int lane = tid & 63;
    int q    = lane >> 4;
    int mi   = lane & 15;
    int m0   = gb * 64 + wave * 16;

    int rho = m0 + mi;
    int t = rho / cN;
    int n = rho - t * cN;
    const float* xr = x + (size_t)n * (cT * cFIN) + t * cFIN;

    bf16x8 afrag[2];
    #pragma unroll
    for (int s = 0; s < 2; s++) {
        float4 v0 = *(const float4*)(xr + s * 32 + q * 8);
        float4 v1 = *(const float4*)(xr + s * 32 + q * 8 + 4);
        bf16x8 f;
        f[0] = (short)f2bfu(v0.x); f[1] = (short)f2bfu(v0.y);
        f[2] = (short)f2bfu(v0.z); f[3] = (short)f2bfu(v0.w);
        f[4] = (short)f2bfu(v1.x); f[5] = (short)f2bfu(v1.y);
        f[6] = (short)f2bfu(v1.z); f[7] = (short)f2bfu(v1.w);
        afrag[s] = f;
    }

    f32x4 acc[8];
    #pragma unroll
    for (int ct = 0; ct < 8; ct++) acc[ct] = (f32x4){0.f, 0.f, 0.f, 0.f};
    #pragma unroll
    for (int ct = 0; ct < 8; ct++) {
        int c = ct * 16 + mi;
        #pragma unroll
        for (int s = 0; s < 2; s++) {
            bf16x8 bfrag = *(const bf16x8*)(W + (size_t)c * cFIN + s * 32 + q * 8);
            acc[ct] = __builtin_amdgcn_mfma_f32_16x16x32_bf16(afrag[s], bfrag, acc[ct], 0, 0, 0);
        }
    }

    // scores from accumulators (fp32, no LDS/barrier)
    #pragma unroll
    for (int h = 0; h < 4; h++) {
        float a0 = a_src[h * 32 + mi], a1 = a_src[h * 32 + 16 + mi];
        float d0 = a_dst[h * 32 + mi], d1 = a_dst[h * 32 + 16 + mi];
        #pragma unroll
        for (int rr = 0; rr < 4; rr++) {
            float vs = acc[2 * h][rr] * a0 + acc[2 * h + 1][rr] * a1;
            float vd = acc[2 * h][rr] * d0 + acc[2 * h + 1][rr] * d1;
            vs += __shfl_xor(vs, 1); vs += __shfl_xor(vs, 2);
            vs += __shfl_xor(vs, 4); vs += __shfl_xor(vs, 8);
            vd += __shfl_xor(vd, 1); vd += __shfl_xor(vd, 2);
            vd += __shfl_xor(vd, 4); vd += __shfl_xor(vd, 8);
            if (mi == 0) {
                int rg = m0 + q * 4 + rr;
                es[rg * cHEADS + h] = vs * cL2E;
                ed[rg * cHEADS + h] = vd * cL2E;
            }
        }
    }

    // direct pi-v2 write: head h's pair (32h+mi, 32h+16+mi) -> dword h*16+mi
    #pragma unroll
    for (int rr = 0; rr < 4; rr++) {
        int rg = m0 + q * 4 + rr;
        unsigned short* hrow = hb + (size_t)rg * cHID;
        #pragma unroll
        for (int h = 0; h < 4; h++) {
            unsigned pv = pack2(acc[2 * h][rr], acc[2 * h + 1][rr]);
            *(unsigned*)(hrow + h * 32 + mi * 2) = pv;
        }
    }
}

// ---------------- agg core: one (row, 8-feature slice) per thread ----------------
// Slice j = storage bytes [16j,16j+16) == head j>>2 only (pi-v2 head-locality).
// scores es/ed pre-scaled by log2(e); w = exp2(leaky(es+ed)). Packed fp32 fma.
// Explicit csr-quad prefetch: next iteration's indices load while the current
// quad's h/es loads and fmas are in flight (removes csr->h serialization).
static __device__ __forceinline__ void agg_core(
        const unsigned short* __restrict__ hb, const float* __restrict__ es,
        const float* __restrict__ ed, const int* __restrict__ offs,
        const int* __restrict__ csr, const float* __restrict__ bias,
        int t, int n, int j, float* r) {
    int head = j >> 2;
    int rho  = t * cN + n;
    int s0 = offs[n], s1 = offs[n + 1];
    float edn = ed[(size_t)rho * cHEADS + head];
    const char* hpc = (const char*)(hb + (size_t)t * cN * cHID);     // plane base
    const char* epc = (const char*)(es + (size_t)t * cN * cHEADS);
    const char* cc  = (const char*)csr;
    unsigned jo = (unsigned)j * 16u;
    unsigned ho = (unsigned)head * 4u;

    f32x2 acc[4];
    #pragma unroll
    for (int k = 0; k < 4; k++) acc[k] = (f32x2){0.f, 0.f};
    float den = 0.f;
    int i = s0;
    int pa = 0, pb = 0, pc2 = 0, pd = 0;
    bool have = (i + 3 < s1);
    if (have) {
        unsigned io = (unsigned)i * 4u;
        pa  = *(const int*)(cc + io);
        pb  = *(const int*)(cc + io + 4u);
        pc2 = *(const int*)(cc + io + 8u);
        pd  = *(const int*)(cc + io + 12u);
    }
    while (have) {
        int sa = pa, sb = pb, sc = pc2, sd = pd;
        uint4 ra = *(const uint4*)(hpc + (((unsigned)sa) << 8) + jo);
        uint4 rb = *(const uint4*)(hpc + (((unsigned)sb) << 8) + jo);
        uint4 rc = *(const uint4*)(hpc + (((unsigned)sc) << 8) + jo);
        uint4 rd = *(const uint4*)(hpc + (((unsigned)sd) << 8) + jo);
        float ea = *(const float*)(epc + (((unsigned)sa) << 4) + ho) + edn;
        float eb = *(const float*)(epc + (((unsigned)sb) << 4) + ho) + edn;
        float ec = *(const float*)(epc + (((unsigned)sc) << 4) + ho) + edn;
        float ee = *(const float*)(epc + (((unsigned)sd) << 4) + ho) + edn;
        i += 4;
        have = (i + 3 < s1);
        if (have) {                      // prefetch next quad under current loads
            unsigned io = (unsigned)i * 4u;
            pa  = *(const int*)(cc + io);
            pb  = *(const int*)(cc + io + 4u);
            pc2 = *(const int*)(cc + io + 8u);
            pd  = *(const int*)(cc + io + 12u);
        }
        ea = (ea >= 0.f) ? ea : cLEAKY * ea;
        eb = (eb >= 0.f) ? eb : cLEAKY * eb;
        ec = (ec >= 0.f) ? ec : cLEAKY * ec;
        ee = (ee >= 0.f) ? ee : cLEAKY * ee;
        float wa = __builtin_amdgcn_exp2f(ea), wb = __builtin_amdgcn_exp2f(eb);
        float wc = __builtin_amdgcn_exp2f(ec), wd = __builtin_amdgcn_exp2f(ee);
        den += wa; den += wb; den += wc; den += wd;
        f32x2 wa2 = (f32x2){wa, wa}, wb2 = (f32x2){wb, wb};
        f32x2 wc2 = (f32x2){wc, wc}, wd2 = (f32x2){wd, wd};
        acc[0] += wa2 * bfp2(ra.x); acc[1] += wa2 * bfp2(ra.y);
        acc[2] += wa2 * bfp2(ra.z); acc[3] += wa2 * bfp2(ra.w);
        acc[0] += wb2 * bfp2(rb.x); acc[1] += wb2 * bfp2(rb.y);
        acc[2] += wb2 * bfp2(rb.z); acc[3] += wb2 * bfp2(rb.w);
        acc[0] += wc2 * bfp2(rc.x); acc[1] += wc2 * bfp2(rc.y);
        acc[2] += wc2 * bfp2(rc.z); acc[3] += wc2 * bfp2(rc.w);
        acc[0] += wd2 * bfp2(rd.x); acc[1] += wd2 * bfp2(rd.y);
        acc[2] += wd2 * bfp2(rd.z); acc[3] += wd2 * bfp2(rd.w);
    }
    for (; i < s1; i++) {
        int sa = *(const int*)(cc + (unsigned)i * 4u);
        uint4 ra = *(const uint4*)(hpc + (((unsigned)sa) << 8) + jo);
        float ea = *(const float*)(epc + (((unsigned)sa) << 4) + ho) + edn;
        ea = (ea >= 0.f) ? ea : cLEAKY * ea;
        float wa = __builtin_amdgcn_exp2f(ea);
        den += wa;
        f32x2 wa2 = (f32x2){wa, wa};
        acc[0] += wa2 * bfp2(ra.x); acc[1] += wa2 * bfp2(ra.y);
        acc[2] += wa2 * bfp2(ra.z); acc[3] += wa2 * bfp2(ra.w);
    }
    float inv = 1.f / (den + 1e-16f);
    float4 b0 = *(const float4*)(bias + 8 * j);
    float4 b1v = *(const float4*)(bias + 8 * j + 4);
    float v0 = acc[0].x * inv + b0.x;  r[0] = (v0 > 0.f) ? v0 : expm1f(v0);
    float v1 = acc[0].y * inv + b0.y;  r[1] = (v1 > 0.f) ? v1 : expm1f(v1);
    float v2 = acc[1].x * inv + b0.z;  r[2] = (v2 > 0.f) ? v2 : expm1f(v2);
    float v3 = acc[1].y * inv + b0.w;  r[3] = (v3 > 0.f) ? v3 : expm1f(v3);
    float v4 = acc[2].x * inv + b1v.x; r[4] = (v4 > 0.f) ? v4 : expm1f(v4);
    float v5 = acc[2].y * inv + b1v.y; r[5] = (v5 > 0.f) ? v5 : expm1f(v5);
    float v6 = acc[3].x * inv + b1v.z; r[6] = (v6 > 0.f) ? v6 : expm1f(v6);
    float v7 = acc[3].y * inv + b1v.w; r[7] = (v7 > 0.f) ? v7 : expm1f(v7);
}

// ---------------- fused agg(layer1) + GEMM2 + scores2 (single barrier) ----------------
// block = (t, 16 degree-matched nodes via windowed perm), t = b&7 (XCD plane affinity).
__global__ __launch_bounds__(256) void agg_gemm_kernel(
        const unsigned short* __restrict__ hb, const float* __restrict__ es,
        const float* __restrict__ ed, const int* __restrict__ offs,
        const int* __restrict__ csr, const int* __restrict__ perm,
        const float* __restrict__ b1P,
        const unsigned short* __restrict__ W2bP, const float* __restrict__ a_src,
        const float* __restrict__ a_dst, unsigned short* __restrict__ hb2,
        float* __restrict__ es2, float* __restrict__ ed2) {
    __shared__ unsigned short tile[16 * 128];   // 4 KB, XOR-swizzled rows
    int b    = blockIdx.x;
    int t    = b & 7;
    int g    = b >> 3;
    int tid  = threadIdx.x;
    int lrow = tid >> 4;
    int j    = tid & 15;
    int n0   = g * 16;
    int n    = perm[n0 + lrow];       // broadcast within 16-lane group, L2-hot

    float r[8];
    agg_core(hb, es, ed, offs, csr, b1P, t, n, j, r);
    {
        uint4 o;
        o.x = pack2(r[0], r[1]); o.y = pack2(r[2], r[3]);
        o.z = pack2(r[4], r[5]); o.w = pack2(r[6], r[7]);
        unsigned tb = (unsigned)lrow * 256u + (((unsigned)j * 16u) ^ (((unsigned)(lrow & 7)) << 4));
        *(uint4*)((char*)tile + tb) = o;
    }
    __syncthreads();

    // ---- in-block GEMM: h2 = x2 @ W2^T (K=128, pi-v2 order on both sides) ----
    int wave = tid >> 6;
    int lane = tid & 63;
    int q    = lane >> 4;
    int mi   = lane & 15;
    bf16x8 afrag[4];
    #pragma unroll
    for (int s = 0; s < 4; s++) {
        unsigned addr = (unsigned)mi * 256u +
                        (((unsigned)(s * 64 + q * 16)) ^ (((unsigned)(mi & 7)) << 4));
        afrag[s] = *(const bf16x8*)((const char*)tile + addr);
    }
    f32x4 acc2[2];
    acc2[0] = (f32x4){0.f, 0.f, 0.f, 0.f};
    acc2[1] = acc2[0];
    #pragma unroll
    for (int ct = 0; ct < 2; ct++) {
        int c = (wave * 2 + ct) * 16 + mi;
        #pragma unroll
        for (int s = 0; s < 4; s++) {
            bf16x8 bfrag = *(const bf16x8*)(W2bP + (size_t)c * cHID + s * 32 + q * 8);
            acc2[ct] = __builtin_amdgcn_mfma_f32_16x16x32_bf16(afrag[s], bfrag, acc2[ct], 0, 0, 0);
        }
    }

    // ---- scores: wave w owns exactly head w's 32 cols (ct pair 2w,2w+1) ----
    {
        float a0 = a_src[wave * 32 + mi], a1 = a_src[wave * 32 + 16 + mi];
        float d0 = a_dst[wave * 32 + mi], d1 = a_dst[wave * 32 + 16 + mi];
        #pragma unroll
        for (int rr = 0; rr < 4; rr++) {
            float vs = acc2[0][rr] * a0 + acc2[1][rr] * a1;
            float vd = acc2[0][rr] * d0 + acc2[1][rr] * d1;
            vs += __shfl_xor(vs, 1); vs += __shfl_xor(vs, 2);
            vs += __shfl_xor(vs, 4); vs += __shfl_xor(vs, 8);
            vd += __shfl_xor(vd, 1); vd += __shfl_xor(vd, 2);
            vd += __shfl_xor(vd, 4); vd += __shfl_xor(vd, 8);
            if (mi == 0) {
                int rg = t * cN + perm[n0 + q * 4 + rr];
                es2[(size_t)rg * cHEADS + wave] = vs * cL2E;
                ed2[(size_t)rg * cHEADS + wave] = vd * cL2E;
            }
        }
    }

    // ---- direct pi-v2 write of h2: head=wave's pair -> dword wave*16 + mi ----
    #pragma unroll
    for (int rr = 0; rr < 4; rr++) {
        int rg = t * cN + perm[n0 + q * 4 + rr];
        unsigned pv = pack2(acc2[0][rr], acc2[1][rr]);
        *(unsigned*)(hb2 + (size_t)rg * cHID + wave * 32 + mi * 2) = pv;
    }
}

// ---------------- fused agg(layer2) + MLP head -> out ----------------
__global__ __launch_bounds__(256) void TemporalGAT_20005957665499_kernel(
        const unsigned short* __restrict__ hb2, const float* __restrict__ es,
        const float* __restrict__ ed, const int* __restrict__ offs,
        const int* __restrict__ csr, const int* __restrict__ perm,
        const float* __restrict__ b2P,
        const unsigned short* __restrict__ lw1bP, const float* __restrict__ lb1,
        const float* __restrict__ lw2, const float* __restrict__ lb2,
        float* __restrict__ out) {
    __shared__ unsigned short tile[16 * 128];
    int b    = blockIdx.x;
    int t    = b & 7;
    int g    = b >> 3;
    int tid  = threadIdx.x;
    int lrow = tid >> 4;
    int j    = tid & 15;
    int n0   = g * 16;
    int n    = perm[n0 + lrow];

    float r[8];
    agg_core(hb2, es, ed, offs, csr, b2P, t, n, j, r);
    {
        uint4 o;
        o.x = pack2(r[0], r[1]); o.y = pack2(r[2], r[3]);
        o.z = pack2(r[4], r[5]); o.w = pack2(r[6], r[7]);
        unsigned tb = (unsigned)lrow * 256u + (((unsigned)j * 16u) ^ (((unsigned)(lrow & 7)) << 4));
        *(uint4*)((char*)tile + tb) = o;
    }
    __syncthreads();

    if (tid < 64) {      // wave 0: 16x128 @ 128x32 MLP (pi-v2 K), then dot with lw2
        int q  = tid >> 4;
        int mi = tid & 15;
        bf16x8 afrag[4];
        #pragma unroll
        for (int s = 0; s < 4; s++) {
            unsigned addr = (unsigned)mi * 256u +
                            (((unsigned)(s * 64 + q * 16)) ^ (((unsigned)(mi & 7)) << 4));
            afrag[s] = *(const bf16x8*)((const char*)tile + addr);
        }
        f32x4 acc2[2];
        acc2[0] = (f32x4){0.f, 0.f, 0.f, 0.f};
        acc2[1] = acc2[0];
        #pragma unroll
        for (int ct = 0; ct < 2; ct++) {
            int c = ct * 16 + mi;
            #pragma unroll
            for (int s = 0; s < 4; s++) {
                bf16x8 bfrag = *(const bf16x8*)(lw1bP + (size_t)c * cHID + s * 32 + q * 8);
                acc2[ct] = __builtin_amdgcn_mfma_f32_16x16x32_bf16(afrag[s], bfrag, acc2[ct], 0, 0, 0);
            }
        }
        float lb1a = lb1[mi], lb1b_ = lb1[16 + mi];
        float lw2a = lw2[mi], lw2b_ = lw2[16 + mi];
        float l2 = lb2[0];
        #pragma unroll
        for (int rr = 0; rr < 4; rr++) {
            float va = fmaxf(acc2[0][rr] + lb1a, 0.f);
            float vb = fmaxf(acc2[1][rr] + lb1b_, 0.f);
            float v = va * lw2a + vb * lw2b_;
            v += __shfl_xor(v, 1);
            v += __shfl_xor(v, 2);
            v += __shfl_xor(v, 4);
            v += __shfl_xor(v, 8);
            if (mi == 0) out[t * cN + perm[n0 + q * 4 + rr]] = v + l2;
        }
    }
}

// ---------------- launch ----------------
extern "C" void kernel_launch(void* const* d_in, const int* in_sizes, int n_in,
                              void* d_out, int out_size, void* d_ws, size_t ws_size,
                              hipStream_t stream) {
    const float* x   = (const float*)d_in[0];   // [N,T,64] fp32
    const int*   ei  = (const int*)d_in[1];
    const float* W1  = (const float*)d_in[2];
    const float* as1 = (const float*)d_in[3];
    const float* ad1 = (const float*)d_in[4];
    const float* b1  = (const float*)d_in[5];
    const float* W2  = (const float*)d_in[6];
    const float* as2 = (const float*)d_in[7];
    const float* ad2 = (const float*)d_in[8];
    const float* b2  = (const float*)d_in[9];
    const float* lw1 = (const float*)d_in[10];
    const float* lb1 = (const float*)d_in[11];
    const float* lw2 = (const float*)d_in[12];
    const float* lb2 = (const float*)d_in[13];
    float* out = (float*)d_out;                 // [T,N,1] fp32 == rho-major
    (void)in_sizes; (void)n_in; (void)out_size; (void)ws_size;

    // workspace carve, 256B-aligned
    char* ws = (char*)d_ws;
    size_t o = 0;
    auto carveN = [&](size_t bytes) { void* p = ws + o; o += (bytes + 255) & ~(size_t)255; return p; };
    unsigned short* hb    = (unsigned short*)carveN((size_t)cR * cHID * 2);   // 41 MB (layer-1 h, pi-v2)
    unsigned short* hb2   = (unsigned short*)carveN((size_t)cR * cHID * 2);   // 41 MB (layer-2 h, pi-v2)
    unsigned short* W1b   = (unsigned short*)carveN((size_t)cHID * cFIN * 2);
    unsigned short* W2bP  = (unsigned short*)carveN((size_t)cHID * cHID * 2);
    unsigned short* lw1bP = (unsigned short*)carveN((size_t)cF * cHID * 2);
    float* b1P     = (float*)carveN((size_t)cHID * 4);
    float* b2P     = (float*)carveN((size_t)cHID * 4);
    float* es1_buf = (float*)carveN((size_t)cR * cHEADS * 4);                 // 2.6 MB each
    float* ed1_buf = (float*)carveN((size_t)cR * cHEADS * 4);
    float* es2_buf = (float*)carveN((size_t)cR * cHEADS * 4);
    float* ed2_buf = (float*)carveN((size_t)cR * cHEADS * 4);
    int*   deg     = (int*)carveN((size_t)cN * 4);
    int*   offs    = (int*)carveN((size_t)(cN + 1) * 4);
    int*   cursor  = (int*)carveN((size_t)cN * 4);
    int*   csr     = (int*)carveN((size_t)cET * 4);
    int*   perm    = (int*)carveN((size_t)cN * 4);

    // ---- weight conversion (+pi-v2 permute) + degree count ----
    hipMemsetAsync(deg, 0, (size_t)cN * 4, stream);
    cvt_deg_kernel<<<(cE + 255) / 256, 256, 0, stream>>>(
        W1, W2, lw1, b1, b2, ei, W1b, W2bP, lw1bP, b1P, b2P, deg);
    scan_kernel<<<1, 256, 0, stream>>>(deg, offs, cursor, perm);
    // ---- CSR scatter + layer-1 GEMM (independent work, one dispatch) ----
    scatter_gemm1_kernel<<<cSCAT + cR / 64, 256, 0, stream>>>(
        ei, cursor, csr, x, W1b, as1, ad1, hb, es1_buf, ed1_buf);
    // ---- agg1 + GEMM2 + scores2 (fused, degree-matched blocks, prefetch) ----
    agg_gemm_kernel<<<(cN / 16) * cT, 256, 0, stream>>>(
        hb, es1_buf, ed1_buf, offs, csr, perm, b1P, W2bP, as2, ad2, hb2, es2_buf, ed2_buf);
    // ---- agg2 + MLP head (fused) -> out ----
    TemporalGAT_20005957665499_kernel<<<(cN / 16) * cT, 256, 0, stream>>>(
        hb2, es2_buf, ed2_buf, offs, csr, perm, b2P, lw1bP, lb1, lw2, lb2, out);
}